// Round 1
// baseline (5255.123 us; speedup 1.0000x reference)
//
#include <hip/hip_runtime.h>
#include <math.h>

// BiLSTM-CRF fp32 reference-faithful implementation, round 1 (correctness first).
// B=64 S=256 V=50000 E=300 H=256 T=13
#define B_    64
#define S_    256
#define E_    300
#define H_    256
#define T_    13
#define G4_   1024   // 4*H
#define D2H_  512    // 2*H

// ---------------- embedding gather ----------------
__global__ __launch_bounds__(64)
void k_embed(const int* __restrict__ x, const float* __restrict__ emb, float* __restrict__ out) {
  int bs = blockIdx.x;                 // b*S + s
  int xv = x[bs];
  const float4* src = (const float4*)(emb + (size_t)xv * E_);
  float4* dst = (float4*)(out + (size_t)bs * E_);
  for (int q = threadIdx.x; q < E_ / 4; q += 64) dst[q] = src[q];   // 300/4 = 75
}

// ---------------- Whh transpose: (dir,row=g*256+u,k) -> (dir,k,u,gate) ----------------
__global__ __launch_bounds__(256)
void k_twhh(const float* __restrict__ Whh, float* __restrict__ Wt) {
  int r = blockIdx.x;                  // 0..2047
  int dir = r >> 10, row = r & 1023;
  int g = row >> 8, u = row & 255;
  int k = threadIdx.x;
  float v = Whh[((size_t)dir * G4_ + row) * H_ + k];
  Wt[(((size_t)dir * H_ + k) * H_ + u) * 4 + g] = v;
}

// ---------------- fp32 tiled GEMM: C = A @ W (+bias), 64x64 tile ----------------
// BNK=1: W is (N,K) row-major -> C = A@W^T.  BNK=0: W is (K,N).
// permute: output row r corresponds to A row (r&63)*S_ + (r>>6)  (r = s*B+b -> A row b*S+s)
template<int BNK>
__global__ __launch_bounds__(256)
void k_gemm64(const float* __restrict__ A, const float* __restrict__ W,
              const float* __restrict__ bias, float* __restrict__ C,
              int M, int N, int K, int permute,
              long wStride, long bStride, long cStride)
{
  __shared__ float As[16][68];
  __shared__ float Bs[16][68];
  int dir = blockIdx.z;
  W    += (size_t)dir * wStride;
  bias += (size_t)dir * bStride;
  C    += (size_t)dir * cStride;
  int tid = threadIdx.x;
  int row0 = blockIdx.y * 64, col0 = blockIdx.x * 64;
  int tx = tid & 15, ty = tid >> 4;
  int mlocal = tid >> 2, kq = (tid & 3) * 4;
  int krow = tid >> 4,  nq = (tid & 15) * 4;
  float acc[4][4];
  #pragma unroll
  for (int i = 0; i < 4; i++)
    #pragma unroll
    for (int j = 0; j < 4; j++) acc[i][j] = 0.f;

  for (int t0 = 0; t0 < K; t0 += 16) {
    // A tile: 64 rows x 16 k
    {
      int gr = row0 + mlocal;
      int ar = permute ? ((gr & 63) * S_ + (gr >> 6)) : gr;
      const float* ap = A + (size_t)ar * K + t0 + kq;
      if (t0 + 16 <= K) {
        float4 v = *(const float4*)ap;
        As[kq+0][mlocal] = v.x; As[kq+1][mlocal] = v.y;
        As[kq+2][mlocal] = v.z; As[kq+3][mlocal] = v.w;
      } else {
        #pragma unroll
        for (int j = 0; j < 4; j++)
          As[kq+j][mlocal] = (t0 + kq + j < K) ? ap[j] : 0.f;
      }
    }
    // B tile
    if (BNK) {
      const float* wp = W + (size_t)(col0 + mlocal) * K + t0 + kq;
      if (t0 + 16 <= K) {
        float4 v = *(const float4*)wp;
        Bs[kq+0][mlocal] = v.x; Bs[kq+1][mlocal] = v.y;
        Bs[kq+2][mlocal] = v.z; Bs[kq+3][mlocal] = v.w;
      } else {
        #pragma unroll
        for (int j = 0; j < 4; j++)
          Bs[kq+j][mlocal] = (t0 + kq + j < K) ? wp[j] : 0.f;
      }
    } else {
      if (t0 + krow < K) {
        float4 v = *(const float4*)(W + (size_t)(t0 + krow) * N + col0 + nq);
        Bs[krow][nq+0] = v.x; Bs[krow][nq+1] = v.y;
        Bs[krow][nq+2] = v.z; Bs[krow][nq+3] = v.w;
      } else {
        Bs[krow][nq+0] = 0.f; Bs[krow][nq+1] = 0.f;
        Bs[krow][nq+2] = 0.f; Bs[krow][nq+3] = 0.f;
      }
    }
    __syncthreads();
    #pragma unroll
    for (int kk = 0; kk < 16; kk++) {
      float4 a = *(const float4*)&As[kk][ty * 4];
      float4 b = *(const float4*)&Bs[kk][tx * 4];
      acc[0][0] += a.x*b.x; acc[0][1] += a.x*b.y; acc[0][2] += a.x*b.z; acc[0][3] += a.x*b.w;
      acc[1][0] += a.y*b.x; acc[1][1] += a.y*b.y; acc[1][2] += a.y*b.z; acc[1][3] += a.y*b.w;
      acc[2][0] += a.z*b.x; acc[2][1] += a.z*b.y; acc[2][2] += a.z*b.z; acc[2][3] += a.z*b.w;
      acc[3][0] += a.w*b.x; acc[3][1] += a.w*b.y; acc[3][2] += a.w*b.z; acc[3][3] += a.w*b.w;
    }
    __syncthreads();
  }
  #pragma unroll
  for (int i = 0; i < 4; i++) {
    int row = row0 + ty * 4 + i;
    float* cp = C + (size_t)row * N + col0 + tx * 4;
    #pragma unroll
    for (int j = 0; j < 4; j++) cp[j] = acc[i][j] + bias[col0 + tx * 4 + j];
  }
}

// ---------------- LSTM recurrence: one WG per (dir, batch-pair) ----------------
// xg: (2,S,B,4H) pre-gates incl. bias. Wt: (dir,k,u,gate) float4-coalesced.
// hout: (B,S,512), fwd -> [0:256], bwd -> [256:512]
__global__ __launch_bounds__(256)
void k_lstm(const float* __restrict__ xg, const float* __restrict__ Wt,
            float* __restrict__ hout)
{
  __shared__ float hs[2][256];
  int tid = threadIdx.x;
  int dir = blockIdx.x >> 5;
  int b0  = (blockIdx.x & 31) * 2;
  const float4* Wt4 = (const float4*)(Wt + (size_t)dir * H_ * G4_);
  hs[0][tid] = 0.f; hs[1][tid] = 0.f;
  float c0 = 0.f, c1 = 0.f;
  __syncthreads();
  for (int it = 0; it < S_; it++) {
    int s = dir ? (S_ - 1 - it) : it;
    const float* xr0 = xg + (((size_t)dir * S_ + s) * B_ + b0) * G4_;
    const float* xr1 = xr0 + G4_;
    float gi0 = xr0[tid], gf0 = xr0[tid+256], gg0 = xr0[tid+512], go0 = xr0[tid+768];
    float gi1 = xr1[tid], gf1 = xr1[tid+256], gg1 = xr1[tid+512], go1 = xr1[tid+768];
    #pragma unroll 8
    for (int k = 0; k < H_; k++) {
      float4 w = Wt4[k * 256 + tid];          // all 4 gate weights for unit tid at k
      float h0 = hs[0][k], h1 = hs[1][k];     // LDS broadcast
      gi0 += h0*w.x; gf0 += h0*w.y; gg0 += h0*w.z; go0 += h0*w.w;
      gi1 += h1*w.x; gf1 += h1*w.y; gg1 += h1*w.z; go1 += h1*w.w;
    }
    float i0 = 1.f/(1.f+expf(-gi0)), f0 = 1.f/(1.f+expf(-gf0)), o0 = 1.f/(1.f+expf(-go0));
    c0 = f0*c0 + i0*tanhf(gg0);
    float h0n = o0*tanhf(c0);
    float i1 = 1.f/(1.f+expf(-gi1)), f1 = 1.f/(1.f+expf(-gf1)), o1 = 1.f/(1.f+expf(-go1));
    c1 = f1*c1 + i1*tanhf(gg1);
    float h1n = o1*tanhf(c1);
    hout[((size_t)b0       * S_ + s) * D2H_ + dir*256 + tid] = h0n;
    hout[((size_t)(b0 + 1) * S_ + s) * D2H_ + dir*256 + tid] = h1n;
    __syncthreads();
    hs[0][tid] = h0n; hs[1][tid] = h1n;
    __syncthreads();
  }
}

// ---------------- block reduction helpers (256 threads) ----------------
__device__ __forceinline__ float bsum(float v, float* sb) {
  int t = threadIdx.x;
  sb[t] = v; __syncthreads();
  for (int s = 128; s; s >>= 1) { if (t < s) sb[t] += sb[t + s]; __syncthreads(); }
  float r = sb[0]; __syncthreads(); return r;
}
__device__ __forceinline__ float bmax(float v, float* sb) {
  int t = threadIdx.x;
  sb[t] = v; __syncthreads();
  for (int s = 128; s; s >>= 1) { if (t < s) sb[t] = fmaxf(sb[t], sb[t + s]); __syncthreads(); }
  float r = sb[0]; __syncthreads(); return r;
}

// ---------------- pos branch: relu(pos@fc1+b1)@fc2+b2 (+pos) -> LN ----------------
__global__ __launch_bounds__(256)
void k_pos(const float* __restrict__ pos, const float* __restrict__ fc1w, const float* __restrict__ fc1b,
           const float* __restrict__ fc2w, const float* __restrict__ fc2b,
           const float* __restrict__ lng, const float* __restrict__ lnb, float* __restrict__ pos_out)
{
  __shared__ float sp[256], sh[256], sb[256];
  int b = blockIdx.x, t = threadIdx.x;
  sp[t] = pos[b * 256 + t];
  __syncthreads();
  float a1 = fc1b[t];
  for (int s = 0; s < 256; s++) a1 += sp[s] * fc1w[s * 256 + t];
  a1 = fmaxf(a1, 0.f);
  sh[t] = a1; __syncthreads();
  float a2 = fc2b[t] + sp[t];                      // residual h + pos
  for (int s = 0; s < 256; s++) a2 += sh[s] * fc2w[s * 256 + t];
  float m   = bsum(a2, sb) * (1.f / 256.f);
  float cen = a2 - m;
  float var = bsum(cen * cen, sb) * (1.f / 256.f);
  pos_out[b * 256 + t] = cen * rsqrtf(var + 1e-5f) * lng[t] + lnb[t];
}

// ---------------- CLN stage A: per-batch scale/shift vectors ----------------
__global__ __launch_bounds__(256)
void k_clnA(const float* __restrict__ pos_out, const float* __restrict__ wd, const float* __restrict__ bd,
            const float* __restrict__ cw, const float* __restrict__ cb,
            float* __restrict__ wvec, float* __restrict__ bbvec)
{
  __shared__ float sp[256];
  int b = blockIdx.x, t = threadIdx.x;
  sp[t] = pos_out[b * 256 + t];
  __syncthreads();
  const float4* wdr = (const float4*)(wd + (size_t)t * 256);
  const float4* bdr = (const float4*)(bd + (size_t)t * 256);
  float aw = 0.f, ab = 0.f;
  for (int q = 0; q < 64; q++) {
    float4 w4 = wdr[q], b4 = bdr[q];
    float s0 = sp[q*4], s1 = sp[q*4+1], s2 = sp[q*4+2], s3 = sp[q*4+3];
    aw += s0*w4.x + s1*w4.y + s2*w4.z + s3*w4.w;
    ab += s0*b4.x + s1*b4.y + s2*b4.z + s3*b4.w;
  }
  wvec [b * 256 + t] = aw + cw[t];
  bbvec[b * 256 + t] = ab + cb[t];
}

// ---------------- CLN stage B: conditional layernorm (eps 1e-12) + sentence dot ----------------
__global__ __launch_bounds__(256)
void k_clnB(const float* __restrict__ oc, const float* __restrict__ wvec, const float* __restrict__ bbvec,
            const float* __restrict__ alw, const float* __restrict__ alb,
            float* __restrict__ outn, float* __restrict__ sentence)
{
  __shared__ float sb[256];
  int bs = blockIdx.x, t = threadIdx.x;
  int b = bs >> 8;
  float v   = oc[(size_t)bs * 256 + t];
  float m   = bsum(v, sb) * (1.f / 256.f);
  float cen = v - m;
  float var = bsum(cen * cen, sb) * (1.f / 256.f);
  float o   = cen * rsqrtf(var + 1e-12f) * wvec[b * 256 + t] + bbvec[b * 256 + t];
  outn[(size_t)bs * 256 + t] = o;
  float sv = bsum(o * alw[t], sb);
  if (t == 0) sentence[bs] = sv + alb[0];
}

// ---------------- attention: Q*K softmax, alpha*V layernorm (per batch over S) ----------------
__global__ __launch_bounds__(256)
void k_att(const float* __restrict__ sentence,
           const float* __restrict__ wq, const float* __restrict__ bq,
           const float* __restrict__ wk, const float* __restrict__ bk,
           const float* __restrict__ wv, const float* __restrict__ bv,
           const float* __restrict__ lng, const float* __restrict__ lnb,
           float* __restrict__ att)
{
  __shared__ float ss[256], sb[256];
  int b = blockIdx.x, t = threadIdx.x;
  ss[t] = sentence[b * 256 + t];
  __syncthreads();
  float q = bq[t], k = bk[t], vv = bv[t];
  for (int s = 0; s < 256; s++) {
    float sv = ss[s];
    q  += sv * wq[s * 256 + t];
    k  += sv * wk[s * 256 + t];
    vv += sv * wv[s * 256 + t];
  }
  float x  = q * k * (1.f / 16.f);      // / sqrt(256)
  float mx = bmax(x, sb);
  float e  = expf(x - mx);
  float sm = bsum(e, sb);
  float a  = (e / sm) * vv;
  float m   = bsum(a, sb) * (1.f / 256.f);
  float cen = a - m;
  float var = bsum(cen * cen, sb) * (1.f / 256.f);
  att[b * 256 + t] = cen * rsqrtf(var + 1e-5f) * lng[t] + lnb[t];
}

// ---------------- logits: att[bs] * (outn_row @ out_w) + out_b ----------------
__global__ __launch_bounds__(64)
void k_out(const float* __restrict__ outn, const float* __restrict__ att,
           const float* __restrict__ ow, const float* __restrict__ ob,
           float* __restrict__ logits)
{
  __shared__ float row[256];
  int bs = blockIdx.x, t = threadIdx.x;
  ((float4*)row)[t] = ((const float4*)(outn + (size_t)bs * 256))[t];
  __syncthreads();
  float a = att[bs];
  if (t < T_) {
    float acc = 0.f;
    for (int c = 0; c < 256; c++) acc += row[c] * ow[c * T_ + t];
    logits[(size_t)bs * T_ + t] = a * acc + ob[t];
  }
}

// ---------------- Viterbi (per batch; hist in LDS; first-max tie-break) ----------------
__global__ __launch_bounds__(64)
void k_viterbi(const float* __restrict__ logits, const float* __restrict__ start,
               const float* __restrict__ endv, const float* __restrict__ trans,
               float* __restrict__ tags)
{
  __shared__ float sc[16];
  __shared__ float str[169];
  __shared__ unsigned char hist[255 * 13];
  __shared__ int tg[256];
  int b = blockIdx.x, t = threadIdx.x;
  for (int i = t; i < 169; i += 64) str[i] = trans[i];
  if (t < 13) sc[t] = start[t] + logits[((size_t)b * 256) * 13 + t];
  __syncthreads();
  for (int s = 1; s < 256; s++) {
    float best = -1e30f; int bi = 0;
    if (t < 13) {
      best = sc[0] + str[t]; bi = 0;
      for (int i = 1; i < 13; i++) {
        float v = sc[i] + str[i * 13 + t];
        if (v > best) { best = v; bi = i; }
      }
    }
    __syncthreads();
    if (t < 13) {
      sc[t] = best + logits[((size_t)b * 256 + s) * 13 + t];
      hist[(s - 1) * 13 + t] = (unsigned char)bi;
    }
    __syncthreads();
  }
  if (t == 0) {
    float best = sc[0] + endv[0]; int last = 0;
    for (int j = 1; j < 13; j++) {
      float v = sc[j] + endv[j];
      if (v > best) { best = v; last = j; }
    }
    tg[255] = last;
    int cur = last;
    for (int s = 254; s >= 0; s--) { cur = hist[s * 13 + cur]; tg[s] = cur; }
  }
  __syncthreads();
  for (int s = t; s < 256; s += 64) tags[b * 256 + s] = (float)tg[s];
}

// ---------------- launch ----------------
extern "C" void kernel_launch(void* const* d_in, const int* in_sizes, int n_in,
                              void* d_out, int out_size, void* d_ws, size_t ws_size,
                              hipStream_t stream)
{
  const int*   x     = (const int*)  d_in[0];
  const float* pos   = (const float*)d_in[1];
  const float* emb   = (const float*)d_in[2];
  const float* Wih0  = (const float*)d_in[3];
  const float* Whh0  = (const float*)d_in[4];
  const float* b0    = (const float*)d_in[5];
  const float* Wih1  = (const float*)d_in[6];
  const float* Whh1  = (const float*)d_in[7];
  const float* b1    = (const float*)d_in[8];
  const float* fc1w  = (const float*)d_in[9];
  const float* fc1b  = (const float*)d_in[10];
  const float* fc2w  = (const float*)d_in[11];
  const float* fc2b  = (const float*)d_in[12];
  const float* plng  = (const float*)d_in[13];
  const float* plnb  = (const float*)d_in[14];
  const float* condw = (const float*)d_in[15];
  const float* condb = (const float*)d_in[16];
  const float* clnw  = (const float*)d_in[17];
  const float* clnb  = (const float*)d_in[18];
  const float* clnwd = (const float*)d_in[19];
  const float* clnbd = (const float*)d_in[20];
  const float* wq    = (const float*)d_in[21];
  const float* bq    = (const float*)d_in[22];
  const float* wk    = (const float*)d_in[23];
  const float* bk    = (const float*)d_in[24];
  const float* wv    = (const float*)d_in[25];
  const float* bv    = (const float*)d_in[26];
  const float* atlng = (const float*)d_in[27];
  const float* atlnb = (const float*)d_in[28];
  const float* alw   = (const float*)d_in[29];
  const float* alb   = (const float*)d_in[30];
  const float* ow    = (const float*)d_in[31];
  const float* ob    = (const float*)d_in[32];
  const float* cstart= (const float*)d_in[33];
  const float* cend  = (const float*)d_in[34];
  const float* ctrans= (const float*)d_in[35];

  const size_t BS = (size_t)B_ * S_;   // 16384
  float* ws = (float*)d_ws;
  // region plan (reuse to fit ws):
  float* r1       = ws;                       // emb_out (BS*300), later out_cond (BS*256)
  float* xg       = r1 + BS * E_;             // 2*BS*1024 (layer0 then layer1 pre-gates)
  float* l0       = xg + 2 * BS * (size_t)G4_;// BS*512, later outn (BS*256)
  float* l1       = l0 + BS * (size_t)D2H_;   // BS*512
  float* pos_out  = l1 + BS * (size_t)D2H_;
  float* wvec     = pos_out + 16384;
  float* bbvec    = wvec + 16384;
  float* sentence = bbvec + 16384;
  float* attv     = sentence + 16384;
  float* wt0      = attv + 16384;             // 2*256*1024 = 524288
  float* wt1      = wt0 + 524288;

  float* emb_out  = r1;
  float* out_cond = r1;
  float* outn     = l0;
  float* logits   = (float*)d_out;            // (B,S,T) fp32
  float* tags     = logits + BS * T_;         // (B,S) written as fp32 values

  k_embed<<<dim3(B_ * S_), dim3(64), 0, stream>>>(x, emb, emb_out);
  k_twhh <<<dim3(2048), dim3(256), 0, stream>>>(Whh0, wt0);
  k_twhh <<<dim3(2048), dim3(256), 0, stream>>>(Whh1, wt1);

  // layer-0 pre-gates: xg = emb_out @ Wih0^T + b0, output rows r = s*B+b
  k_gemm64<1><<<dim3(G4_ / 64, (B_ * S_) / 64, 2), dim3(256), 0, stream>>>(
      emb_out, Wih0, b0, xg, B_ * S_, G4_, E_, 1,
      (long)G4_ * E_, (long)G4_, (long)B_ * S_ * G4_);
  k_lstm<<<dim3(64), dim3(256), 0, stream>>>(xg, wt0, l0);

  // layer-1 pre-gates from concat(h_fwd,h_bwd)
  k_gemm64<1><<<dim3(G4_ / 64, (B_ * S_) / 64, 2), dim3(256), 0, stream>>>(
      l0, Wih1, b1, xg, B_ * S_, G4_, D2H_, 1,
      (long)G4_ * D2H_, (long)G4_, (long)B_ * S_ * G4_);
  k_lstm<<<dim3(64), dim3(256), 0, stream>>>(xg, wt1, l1);

  // cond projection: (B,S,512) @ (512,256) + b
  k_gemm64<0><<<dim3(S_ / 64, (B_ * S_) / 64, 1), dim3(256), 0, stream>>>(
      l1, condw, condb, out_cond, B_ * S_, S_, D2H_, 0, 0, 0, 0);

  k_pos <<<dim3(B_), dim3(256), 0, stream>>>(pos, fc1w, fc1b, fc2w, fc2b, plng, plnb, pos_out);
  k_clnA<<<dim3(B_), dim3(256), 0, stream>>>(pos_out, clnwd, clnbd, clnw, clnb, wvec, bbvec);
  k_clnB<<<dim3(B_ * S_), dim3(256), 0, stream>>>(out_cond, wvec, bbvec, alw, alb, outn, sentence);
  k_att <<<dim3(B_), dim3(256), 0, stream>>>(sentence, wq, bq, wk, bk, wv, bv, atlng, atlnb, attv);
  k_out <<<dim3(B_ * S_), dim3(64), 0, stream>>>(outn, attv, ow, ob, logits);
  k_viterbi<<<dim3(B_), dim3(64), 0, stream>>>(logits, cstart, cend, ctrans, tags);
}